// Round 2
// baseline (518.272 us; speedup 1.0000x reference)
//
#include <hip/hip_runtime.h>

typedef _Float16 f16;
typedef __attribute__((ext_vector_type(8))) _Float16 h8;
typedef __attribute__((ext_vector_type(4))) _Float16 h4;
typedef __attribute__((ext_vector_type(4))) float f4;

#define MFMA(a, b, c) __builtin_amdgcn_mfma_f32_16x16x32_f16(a, b, c, 0, 0, 0)

__device__ __forceinline__ void gload16(const void* g, void* l) {
    __builtin_amdgcn_global_load_lds((const __attribute__((address_space(1))) void*)g,
                                     (__attribute__((address_space(3))) void*)l, 16, 0, 0);
}

__device__ __forceinline__ float rmax16(float v) {
#pragma unroll
    for (int m = 1; m < 16; m <<= 1) v = fmaxf(v, __shfl_xor(v, m));
    return v;
}
__device__ __forceinline__ float rsum16(float v) {
#pragma unroll
    for (int m = 1; m < 16; m <<= 1) v += __shfl_xor(v, m);
    return v;
}

// ---------------- conversion kernels ----------------

__global__ __launch_bounds__(256) void cvt_f16_kernel(const float* __restrict__ in,
                                                      f16* __restrict__ out, int n8) {
    int i = blockIdx.x * blockDim.x + threadIdx.x;
    if (i >= n8) return;
    const float4* p = (const float4*)in + (size_t)i * 2;
    float4 a = p[0], b = p[1];
    h8 o;
    o[0] = (f16)a.x; o[1] = (f16)a.y; o[2] = (f16)a.z; o[3] = (f16)a.w;
    o[4] = (f16)b.x; o[5] = (f16)b.y; o[6] = (f16)b.z; o[7] = (f16)b.w;
    *((h8*)out + i) = o;
}

// in: [R][Cc] f32 row-major -> out: [Cc][R] f16 row-major
__global__ __launch_bounds__(256) void transpose_cvt(const float* __restrict__ in,
                                                     f16* __restrict__ out, int R, int Cc) {
    __shared__ float tile[32][33];
    int tx = threadIdx.x, ty = threadIdx.y;
    int c0 = blockIdx.x * 32, r0 = blockIdx.y * 32;
#pragma unroll
    for (int k = 0; k < 32; k += 8)
        tile[ty + k][tx] = in[(size_t)(r0 + ty + k) * Cc + c0 + tx];
    __syncthreads();
#pragma unroll
    for (int k = 0; k < 32; k += 8)
        out[(size_t)(c0 + ty + k) * R + r0 + tx] = (f16)tile[tx][ty + k];
}

// ---------------- GEMM core (128x128 tile, BK=64, 4 waves, swizzled LDS) ----------------

__device__ __forceinline__ void gemm_core(const f16* __restrict__ A, const f16* __restrict__ Bt,
                                          int K, int m0, int n0,
                                          f16* lA, f16* lB, f4 acc[4][4]) {
    const int tid = threadIdx.x, lane = tid & 63, wave = tid >> 6;
    const int wm = (wave >> 1) * 64, wn = (wave & 1) * 64;
    for (int k0 = 0; k0 < K; k0 += 64) {
        __syncthreads();
#pragma unroll
        for (int i = 0; i < 4; i++) {
            int s = i * 256 + wave * 64 + lane;
            int row = s >> 3;
            int gc = ((s & 7) ^ (row & 7)) * 8;
            gload16(A + (size_t)(m0 + row) * K + k0 + gc, lA + (i * 256 + wave * 64) * 8);
        }
#pragma unroll
        for (int i = 0; i < 4; i++) {
            int s = i * 256 + wave * 64 + lane;
            int row = s >> 3;
            int gc = ((s & 7) ^ (row & 7)) * 8;
            gload16(Bt + (size_t)(n0 + row) * K + k0 + gc, lB + (i * 256 + wave * 64) * 8);
        }
        __syncthreads();
#pragma unroll
        for (int kk = 0; kk < 2; kk++) {
            h8 af[4], bg[4];
#pragma unroll
            for (int im = 0; im < 4; im++) {
                int row = wm + im * 16 + (lane & 15);
                int pc = (kk * 4 + (lane >> 4)) ^ (row & 7);
                af[im] = *(const h8*)(lA + row * 64 + pc * 8);
            }
#pragma unroll
            for (int in = 0; in < 4; in++) {
                int row = wn + in * 16 + (lane & 15);
                int pc = (kk * 4 + (lane >> 4)) ^ (row & 7);
                bg[in] = *(const h8*)(lB + row * 64 + pc * 8);
            }
#pragma unroll
            for (int im = 0; im < 4; im++)
#pragma unroll
                for (int in = 0; in < 4; in++)
                    acc[im][in] = MFMA(af[im], bg[in], acc[im][in]);
        }
    }
}

// ---------------- QKV GEMM: writes Q,K [BH][T][64], V transposed [BH][64][T] ----------------

__global__ __launch_bounds__(256) void qkv_gemm(const f16* __restrict__ A, const f16* __restrict__ Bt,
                                                const float* __restrict__ bias,
                                                f16* __restrict__ Qo, f16* __restrict__ Ko,
                                                f16* __restrict__ Vo) {
    __shared__ f16 lA[128 * 64], lB[128 * 64];
    f4 acc[4][4];
    const f4 zz = {0.f, 0.f, 0.f, 0.f};
#pragma unroll
    for (int i = 0; i < 4; i++)
#pragma unroll
        for (int j = 0; j < 4; j++) acc[i][j] = zz;

    const int nb = blockIdx.x % 24, mb = blockIdx.x / 24;
    gemm_core(A, Bt, 1024, mb * 128, nb * 128, lA, lB, acc);

    const int lane = threadIdx.x & 63, wave = threadIdx.x >> 6;
    const int wm = (wave >> 1) * 64, wn = (wave & 1) * 64;
#pragma unroll
    for (int im = 0; im < 4; im++) {
        int m4 = mb * 128 + wm + im * 16 + (lane >> 4) * 4;
        int b = m4 >> 11, t0 = m4 & 2047;
#pragma unroll
        for (int in = 0; in < 4; in++) {
            int n = nb * 128 + wn + in * 16 + (lane & 15);
            float bb = bias[n];
            int sec = n >> 10, cc = n & 1023, hh = cc >> 6, d = cc & 63;
            if (sec == 2) {
                h4 pv;
#pragma unroll
                for (int r = 0; r < 4; r++) pv[r] = (f16)(acc[im][in][r] + bb);
                *(h4*)(Vo + ((size_t)(b * 16 + hh) * 64 + d) * 2048 + t0) = pv;
            } else {
                f16* dst = sec ? Ko : Qo;
                size_t base = ((size_t)(b * 16 + hh) * 2048 + t0) * 64 + d;
#pragma unroll
                for (int r = 0; r < 4; r++) dst[base + (size_t)r * 64] = (f16)(acc[im][in][r] + bb);
            }
        }
    }
}

// ---------------- Proj GEMM: f32 output + bias ----------------

__global__ __launch_bounds__(256) void proj_gemm(const f16* __restrict__ A, const f16* __restrict__ Bt,
                                                 const float* __restrict__ bias,
                                                 float* __restrict__ out) {
    __shared__ f16 lA[128 * 64], lB[128 * 64];
    f4 acc[4][4];
    const f4 zz = {0.f, 0.f, 0.f, 0.f};
#pragma unroll
    for (int i = 0; i < 4; i++)
#pragma unroll
        for (int j = 0; j < 4; j++) acc[i][j] = zz;

    const int nb = blockIdx.x & 7, mb = blockIdx.x >> 3;
    gemm_core(A, Bt, 1024, mb * 128, nb * 128, lA, lB, acc);

    const int lane = threadIdx.x & 63, wave = threadIdx.x >> 6;
    const int wm = (wave >> 1) * 64, wn = (wave & 1) * 64;
#pragma unroll
    for (int im = 0; im < 4; im++) {
        int m4 = mb * 128 + wm + im * 16 + (lane >> 4) * 4;
#pragma unroll
        for (int in = 0; in < 4; in++) {
            int n = nb * 128 + wn + in * 16 + (lane & 15);
            float bb = bias[n];
#pragma unroll
            for (int r = 0; r < 4; r++)
                out[(size_t)(m4 + r) * 1024 + n] = acc[im][in][r] + bb;
        }
    }
}

// ---------------- Flash attention (causal) ----------------
// Q,K: [BH][2048][64] f16; Vg: [BH][64][2048] f16 (transposed); O: [B][2048][1024] f16
// 1 block = 128 q-rows; 4 waves x 32 rows; KV tiles of 64.
// K: double-buffered LDS via global_load_lds + counted vmcnt (T4).
// V: direct from global (L2-resident tile; staging would be pure overhead).
// qb permutation: every stride-4 group of 4 qbs sums to 68 tiles -> per-CU balance.

#define ASM_VMCNT(N) asm volatile("s_waitcnt vmcnt(" #N ")" ::: "memory")

__global__ __launch_bounds__(256, 4) void attn_kernel(const f16* __restrict__ Q, const f16* __restrict__ K,
                                                      const f16* __restrict__ Vg, f16* __restrict__ O) {
    __shared__ f16 lK[2][64 * 64];
    __shared__ f16 lP[4 * 32 * 64];
    const int tid = threadIdx.x, lane = tid & 63, wave = tid >> 6;
    const int bh = blockIdx.x & 63;
    const int g = blockIdx.x >> 6;
    const int qb = (int)((0x75318ACE64209BDFull >> (g * 4)) & 15);
    const int q0 = qb * 128;
    const int qw = q0 + wave * 32;
    const f16* Qb = Q + (size_t)bh * 2048 * 64;
    const f16* Kb = K + (size_t)bh * 2048 * 64;
    const f16* Vb = Vg + (size_t)bh * 64 * 2048;
    f16* lPw = lP + wave * 32 * 64;

    // hoist Q fragments (A-operand layout)
    h8 qf[2][2];
#pragma unroll
    for (int im = 0; im < 2; im++)
#pragma unroll
        for (int kk = 0; kk < 2; kk++) {
            int t = qw + im * 16 + (lane & 15);
            qf[im][kk] = *(const h8*)(Qb + (size_t)t * 64 + kk * 32 + (lane >> 4) * 8);
        }

    float mrun[2][4], lrun[2][4];
    f4 yacc[2][4];
    const f4 zz = {0.f, 0.f, 0.f, 0.f};
#pragma unroll
    for (int im = 0; im < 2; im++) {
#pragma unroll
        for (int r = 0; r < 4; r++) { mrun[im][r] = -3e38f; lrun[im][r] = 0.f; }
#pragma unroll
        for (int dn = 0; dn < 4; dn++) yacc[im][dn] = zz;
    }

    const int nt = q0 / 64 + 2;

    // prologue: stage tile 0 into buffer 0
#pragma unroll
    for (int i = 0; i < 2; i++) {
        int s = i * 256 + wave * 64 + lane;
        int row = s >> 3;
        int gc = ((s & 7) ^ (row & 7)) * 8;
        gload16(Kb + (size_t)row * 64 + gc, &lK[0][(i * 256 + wave * 64) * 8]);
    }

    for (int it = 0; it < nt; it++) {
        const int cur = it & 1;
        const int k0 = it * 64;

        if (it + 1 < nt) {
            // stage next K tile into the other buffer; its loads stay in flight
#pragma unroll
            for (int i = 0; i < 2; i++) {
                int s = i * 256 + wave * 64 + lane;
                int row = s >> 3;
                int gc = ((s & 7) ^ (row & 7)) * 8;
                gload16(Kb + (size_t)(k0 + 64 + row) * 64 + gc, &lK[cur ^ 1][(i * 256 + wave * 64) * 8]);
            }
            ASM_VMCNT(2);  // wait only for current tile's 2 loads
        } else {
            ASM_VMCNT(0);
        }
        __builtin_amdgcn_sched_barrier(0);
        __builtin_amdgcn_s_barrier();
        __builtin_amdgcn_sched_barrier(0);

        // S = Q K^T
        f4 sacc[2][4];
#pragma unroll
        for (int im = 0; im < 2; im++)
#pragma unroll
            for (int in = 0; in < 4; in++) sacc[im][in] = zz;
#pragma unroll
        for (int kk = 0; kk < 2; kk++) {
            h8 kf[4];
#pragma unroll
            for (int in = 0; in < 4; in++) {
                int row = in * 16 + (lane & 15);
                int pc = (kk * 4 + (lane >> 4)) ^ (row & 7);
                kf[in] = *(const h8*)(&lK[cur][0] + row * 64 + pc * 8);
            }
#pragma unroll
            for (int im = 0; im < 2; im++)
#pragma unroll
                for (int in = 0; in < 4; in++)
                    sacc[im][in] = MFMA(qf[im][kk], kf[in], sacc[im][in]);
        }

        const bool msk = (k0 + 63 > qw);
#pragma unroll
        for (int im = 0; im < 2; im++) {
#pragma unroll
            for (int r = 0; r < 4; r++) {
                float vmax = -3e38f;
#pragma unroll
                for (int in = 0; in < 4; in++) {
                    float s = sacc[im][in][r] * 0.125f;
                    if (msk) {
                        int q = qw + im * 16 + (lane >> 4) * 4 + r;
                        int k = k0 + in * 16 + (lane & 15);
                        if (k > q) s = -3e38f;
                    }
                    sacc[im][in][r] = s;
                    vmax = fmaxf(vmax, s);
                }
                vmax = rmax16(vmax);
                float mnew = fmaxf(mrun[im][r], vmax);
                float scal = __expf(mrun[im][r] - mnew);
                float ls = 0.f;
#pragma unroll
                for (int in = 0; in < 4; in++) {
                    float p = __expf(sacc[im][in][r] - mnew);
                    sacc[im][in][r] = p;
                    ls += p;
                }
                ls = rsum16(ls);
                lrun[im][r] = lrun[im][r] * scal + ls;
                mrun[im][r] = mnew;
#pragma unroll
                for (int dn = 0; dn < 4; dn++) yacc[im][dn][r] *= scal;
            }
        }

        // write P (f16) to per-wave swizzled LDS
#pragma unroll
        for (int im = 0; im < 2; im++)
#pragma unroll
            for (int in = 0; in < 4; in++)
#pragma unroll
                for (int r = 0; r < 4; r++) {
                    int row = im * 16 + (lane >> 4) * 4 + r;
                    int col = in * 16 + (lane & 15);
                    lPw[row * 64 + (((col >> 3) ^ (row & 7)) * 8) + (col & 7)] =
                        (f16)sacc[im][in][r];
                }

        // Y += P V   (V fragments direct from global; tile is L2-resident)
#pragma unroll
        for (int kk = 0; kk < 2; kk++) {
            h8 pf[2], vf[4];
#pragma unroll
            for (int dn = 0; dn < 4; dn++)
                vf[dn] = *(const h8*)(Vb + (size_t)(dn * 16 + (lane & 15)) * 2048 + k0 + kk * 32 +
                                      (lane >> 4) * 8);
#pragma unroll
            for (int im = 0; im < 2; im++) {
                int row = im * 16 + (lane & 15);
                int pc = (kk * 4 + (lane >> 4)) ^ (row & 7);
                pf[im] = *(const h8*)(lPw + row * 64 + pc * 8);
            }
#pragma unroll
            for (int im = 0; im < 2; im++)
#pragma unroll
                for (int dn = 0; dn < 4; dn++)
                    yacc[im][dn] = MFMA(pf[im], vf[dn], yacc[im][dn]);
        }

        // drain LDS reads before other waves may overwrite lK[cur] next iteration
        asm volatile("s_waitcnt lgkmcnt(0)" ::: "memory");
        __builtin_amdgcn_sched_barrier(0);
        __builtin_amdgcn_s_barrier();
        __builtin_amdgcn_sched_barrier(0);
    }

    const int b = bh >> 4, hh = bh & 15;
#pragma unroll
    for (int im = 0; im < 2; im++)
#pragma unroll
        for (int dn = 0; dn < 4; dn++) {
#pragma unroll
            for (int r = 0; r < 4; r++) {
                int q = qw + im * 16 + (lane >> 4) * 4 + r;
                int d = dn * 16 + (lane & 15);
                O[((size_t)(b * 2048 + q)) * 1024 + hh * 64 + d] =
                    (f16)(yacc[im][dn][r] / lrun[im][r]);
            }
        }
}

// ---------------- launch ----------------

extern "C" void kernel_launch(void* const* d_in, const int* in_sizes, int n_in,
                              void* d_out, int out_size, void* d_ws, size_t ws_size,
                              hipStream_t stream) {
    const float* x      = (const float*)d_in[0];
    const float* W_attn = (const float*)d_in[1];
    const float* b_attn = (const float*)d_in[2];
    const float* W_proj = (const float*)d_in[3];
    const float* b_proj = (const float*)d_in[4];
    float* out = (float*)d_out;

    char* ws = (char*)d_ws;
    f16* xb  = (f16*)ws;                                   // 16 MB (reused as attn out)
    f16* Wat = (f16*)(ws + 16777216);                      // 6 MB
    f16* Wpt = (f16*)(ws + 16777216 + 6291456);            // 2 MB
    f16* Vt  = (f16*)(ws + 16777216 + 6291456 + 2097152);  // 16 MB
    f16* Qs  = (f16*)d_out;                                // scratch: first 16 MB of out
    f16* Ks  = (f16*)((char*)d_out + 16777216);            // scratch: second 16 MB of out

    cvt_f16_kernel<<<4096, 256, 0, stream>>>(x, xb, 1048576);
    transpose_cvt<<<dim3(96, 32), dim3(32, 8), 0, stream>>>(W_attn, Wat, 1024, 3072);
    transpose_cvt<<<dim3(32, 32), dim3(32, 8), 0, stream>>>(W_proj, Wpt, 1024, 1024);
    qkv_gemm<<<1536, 256, 0, stream>>>(xb, Wat, b_attn, Qs, Ks, Vt);
    attn_kernel<<<1024, 256, 0, stream>>>(Qs, Ks, Vt, xb);
    proj_gemm<<<512, 256, 0, stream>>>(xb, Wpt, b_proj, out);
}

// Round 3
// 251.280 us; speedup vs baseline: 2.0625x; 2.0625x over previous
//
#include <hip/hip_runtime.h>

typedef _Float16 f16;
typedef __attribute__((ext_vector_type(8))) _Float16 h8;
typedef __attribute__((ext_vector_type(4))) _Float16 h4;
typedef __attribute__((ext_vector_type(4))) float f4;

#define MFMA(a, b, c) __builtin_amdgcn_mfma_f32_16x16x32_f16(a, b, c, 0, 0, 0)

__device__ __forceinline__ void gload16(const void* g, void* l) {
    __builtin_amdgcn_global_load_lds((const __attribute__((address_space(1))) void*)g,
                                     (__attribute__((address_space(3))) void*)l, 16, 0, 0);
}

__device__ __forceinline__ float rmax16(float v) {
#pragma unroll
    for (int m = 1; m < 16; m <<= 1) v = fmaxf(v, __shfl_xor(v, m));
    return v;
}
__device__ __forceinline__ float rsum16(float v) {
#pragma unroll
    for (int m = 1; m < 16; m <<= 1) v += __shfl_xor(v, m);
    return v;
}

// ---------------- conversion kernels ----------------

__global__ __launch_bounds__(256) void cvt_f16_kernel(const float* __restrict__ in,
                                                      f16* __restrict__ out, int n8) {
    int i = blockIdx.x * blockDim.x + threadIdx.x;
    if (i >= n8) return;
    const float4* p = (const float4*)in + (size_t)i * 2;
    float4 a = p[0], b = p[1];
    h8 o;
    o[0] = (f16)a.x; o[1] = (f16)a.y; o[2] = (f16)a.z; o[3] = (f16)a.w;
    o[4] = (f16)b.x; o[5] = (f16)b.y; o[6] = (f16)b.z; o[7] = (f16)b.w;
    *((h8*)out + i) = o;
}

// in: [R][Cc] f32 row-major -> out: [Cc][R] f16 row-major
__global__ __launch_bounds__(256) void transpose_cvt(const float* __restrict__ in,
                                                     f16* __restrict__ out, int R, int Cc) {
    __shared__ float tile[32][33];
    int tx = threadIdx.x, ty = threadIdx.y;
    int c0 = blockIdx.x * 32, r0 = blockIdx.y * 32;
#pragma unroll
    for (int k = 0; k < 32; k += 8)
        tile[ty + k][tx] = in[(size_t)(r0 + ty + k) * Cc + c0 + tx];
    __syncthreads();
#pragma unroll
    for (int k = 0; k < 32; k += 8)
        out[(size_t)(c0 + ty + k) * R + r0 + tx] = (f16)tile[tx][ty + k];
}

// ---------------- GEMM core (128x128 tile, BK=64, 4 waves, swizzled LDS) ----------------

__device__ __forceinline__ void gemm_core(const f16* __restrict__ A, const f16* __restrict__ Bt,
                                          int K, int m0, int n0,
                                          f16* lA, f16* lB, f4 acc[4][4]) {
    const int tid = threadIdx.x, lane = tid & 63, wave = tid >> 6;
    const int wm = (wave >> 1) * 64, wn = (wave & 1) * 64;
    for (int k0 = 0; k0 < K; k0 += 64) {
        __syncthreads();
#pragma unroll
        for (int i = 0; i < 4; i++) {
            int s = i * 256 + wave * 64 + lane;
            int row = s >> 3;
            int gc = ((s & 7) ^ (row & 7)) * 8;
            gload16(A + (size_t)(m0 + row) * K + k0 + gc, lA + (i * 256 + wave * 64) * 8);
        }
#pragma unroll
        for (int i = 0; i < 4; i++) {
            int s = i * 256 + wave * 64 + lane;
            int row = s >> 3;
            int gc = ((s & 7) ^ (row & 7)) * 8;
            gload16(Bt + (size_t)(n0 + row) * K + k0 + gc, lB + (i * 256 + wave * 64) * 8);
        }
        __syncthreads();
#pragma unroll
        for (int kk = 0; kk < 2; kk++) {
            h8 af[4], bg[4];
#pragma unroll
            for (int im = 0; im < 4; im++) {
                int row = wm + im * 16 + (lane & 15);
                int pc = (kk * 4 + (lane >> 4)) ^ (row & 7);
                af[im] = *(const h8*)(lA + row * 64 + pc * 8);
            }
#pragma unroll
            for (int in = 0; in < 4; in++) {
                int row = wn + in * 16 + (lane & 15);
                int pc = (kk * 4 + (lane >> 4)) ^ (row & 7);
                bg[in] = *(const h8*)(lB + row * 64 + pc * 8);
            }
#pragma unroll
            for (int im = 0; im < 4; im++)
#pragma unroll
                for (int in = 0; in < 4; in++)
                    acc[im][in] = MFMA(af[im], bg[in], acc[im][in]);
        }
    }
}

// ---------------- QKV GEMM: writes Q,K [BH][T][64], V transposed [BH][64][T] ----------------

__global__ __launch_bounds__(256) void qkv_gemm(const f16* __restrict__ A, const f16* __restrict__ Bt,
                                                const float* __restrict__ bias,
                                                f16* __restrict__ Qo, f16* __restrict__ Ko,
                                                f16* __restrict__ Vo) {
    __shared__ f16 lA[128 * 64], lB[128 * 64];
    f4 acc[4][4];
    const f4 zz = {0.f, 0.f, 0.f, 0.f};
#pragma unroll
    for (int i = 0; i < 4; i++)
#pragma unroll
        for (int j = 0; j < 4; j++) acc[i][j] = zz;

    const int nb = blockIdx.x % 24, mb = blockIdx.x / 24;
    gemm_core(A, Bt, 1024, mb * 128, nb * 128, lA, lB, acc);

    const int lane = threadIdx.x & 63, wave = threadIdx.x >> 6;
    const int wm = (wave >> 1) * 64, wn = (wave & 1) * 64;
#pragma unroll
    for (int im = 0; im < 4; im++) {
        int m4 = mb * 128 + wm + im * 16 + (lane >> 4) * 4;
        int b = m4 >> 11, t0 = m4 & 2047;
#pragma unroll
        for (int in = 0; in < 4; in++) {
            int n = nb * 128 + wn + in * 16 + (lane & 15);
            float bb = bias[n];
            int sec = n >> 10, cc = n & 1023, hh = cc >> 6, d = cc & 63;
            if (sec == 2) {
                h4 pv;
#pragma unroll
                for (int r = 0; r < 4; r++) pv[r] = (f16)(acc[im][in][r] + bb);
                *(h4*)(Vo + ((size_t)(b * 16 + hh) * 64 + d) * 2048 + t0) = pv;
            } else {
                f16* dst = sec ? Ko : Qo;
                size_t base = ((size_t)(b * 16 + hh) * 2048 + t0) * 64 + d;
#pragma unroll
                for (int r = 0; r < 4; r++) dst[base + (size_t)r * 64] = (f16)(acc[im][in][r] + bb);
            }
        }
    }
}

// ---------------- Proj GEMM: f32 output + bias ----------------

__global__ __launch_bounds__(256) void proj_gemm(const f16* __restrict__ A, const f16* __restrict__ Bt,
                                                 const float* __restrict__ bias,
                                                 float* __restrict__ out) {
    __shared__ f16 lA[128 * 64], lB[128 * 64];
    f4 acc[4][4];
    const f4 zz = {0.f, 0.f, 0.f, 0.f};
#pragma unroll
    for (int i = 0; i < 4; i++)
#pragma unroll
        for (int j = 0; j < 4; j++) acc[i][j] = zz;

    const int nb = blockIdx.x & 7, mb = blockIdx.x >> 3;
    gemm_core(A, Bt, 1024, mb * 128, nb * 128, lA, lB, acc);

    const int lane = threadIdx.x & 63, wave = threadIdx.x >> 6;
    const int wm = (wave >> 1) * 64, wn = (wave & 1) * 64;
#pragma unroll
    for (int im = 0; im < 4; im++) {
        int m4 = mb * 128 + wm + im * 16 + (lane >> 4) * 4;
#pragma unroll
        for (int in = 0; in < 4; in++) {
            int n = nb * 128 + wn + in * 16 + (lane & 15);
            float bb = bias[n];
#pragma unroll
            for (int r = 0; r < 4; r++)
                out[(size_t)(m4 + r) * 1024 + n] = acc[im][in][r] + bb;
        }
    }
}

// ---------------- Flash attention (causal) ----------------
// Q,K: [BH][2048][64] f16; Vg: [BH][64][2048] f16 (transposed); O: [B][2048][1024] f16
// 1 block = 128 q-rows; 4 waves x 32 rows; KV tiles of 64.
// K,V double-buffered LDS via global_load_lds + counted vmcnt(4).
// Per-lane partial softmax denominator; 16-lane sum reduce ONCE after the loop.
// qb permutation interleaves heavy/light blocks for per-CU balance.

#define ASM_VMCNT(N) asm volatile("s_waitcnt vmcnt(" #N ")" ::: "memory")

__global__ __launch_bounds__(256) void attn_kernel(const f16* __restrict__ Q, const f16* __restrict__ K,
                                                   const f16* __restrict__ Vg, f16* __restrict__ O) {
    __shared__ f16 lK[2][64 * 64];
    __shared__ f16 lV[2][64 * 64];
    __shared__ f16 lP[4 * 32 * 64];
    const int tid = threadIdx.x, lane = tid & 63, wave = tid >> 6;
    const int bh = blockIdx.x & 63;
    const int g = blockIdx.x >> 6;
    const int qb = (int)((0x75318ACE64209BDFull >> (g * 4)) & 15);
    const int q0 = qb * 128;
    const int qw = q0 + wave * 32;
    const f16* Qb = Q + (size_t)bh * 2048 * 64;
    const f16* Kb = K + (size_t)bh * 2048 * 64;
    const f16* Vb = Vg + (size_t)bh * 64 * 2048;
    f16* lPw = lP + wave * 32 * 64;

    // hoist Q fragments (A-operand layout)
    h8 qf[2][2];
#pragma unroll
    for (int im = 0; im < 2; im++)
#pragma unroll
        for (int kk = 0; kk < 2; kk++) {
            int t = qw + im * 16 + (lane & 15);
            qf[im][kk] = *(const h8*)(Qb + (size_t)t * 64 + kk * 32 + (lane >> 4) * 8);
        }

    float mrun[2][4], lpart[2][4];
    f4 yacc[2][4];
    const f4 zz = {0.f, 0.f, 0.f, 0.f};
#pragma unroll
    for (int im = 0; im < 2; im++) {
#pragma unroll
        for (int r = 0; r < 4; r++) { mrun[im][r] = -3e38f; lpart[im][r] = 0.f; }
#pragma unroll
        for (int dn = 0; dn < 4; dn++) yacc[im][dn] = zz;
    }

    const int nt = q0 / 64 + 2;

    // prologue: stage tile 0 into buffer 0 (2 K-loads + 2 V-loads)
#pragma unroll
    for (int i = 0; i < 2; i++) {
        int s = i * 256 + wave * 64 + lane;
        int row = s >> 3;
        int gc = ((s & 7) ^ (row & 7)) * 8;
        gload16(Kb + (size_t)row * 64 + gc, &lK[0][(i * 256 + wave * 64) * 8]);
        gload16(Vb + (size_t)row * 2048 + gc, &lV[0][(i * 256 + wave * 64) * 8]);
    }

    for (int it = 0; it < nt; it++) {
        const int cur = it & 1;
        const int k0 = it * 64;

        if (it + 1 < nt) {
            // stage next tile into the other buffer; its loads stay in flight
#pragma unroll
            for (int i = 0; i < 2; i++) {
                int s = i * 256 + wave * 64 + lane;
                int row = s >> 3;
                int gc = ((s & 7) ^ (row & 7)) * 8;
                gload16(Kb + (size_t)(k0 + 64 + row) * 64 + gc, &lK[cur ^ 1][(i * 256 + wave * 64) * 8]);
                gload16(Vb + (size_t)row * 2048 + (k0 + 64) + gc, &lV[cur ^ 1][(i * 256 + wave * 64) * 8]);
            }
            ASM_VMCNT(4);  // wait only for current tile's 4 loads
        } else {
            ASM_VMCNT(0);
        }
        __builtin_amdgcn_sched_barrier(0);
        __builtin_amdgcn_s_barrier();
        __builtin_amdgcn_sched_barrier(0);

        // S = Q K^T
        f4 sacc[2][4];
#pragma unroll
        for (int im = 0; im < 2; im++)
#pragma unroll
            for (int in = 0; in < 4; in++) sacc[im][in] = zz;
        __builtin_amdgcn_s_setprio(1);
#pragma unroll
        for (int kk = 0; kk < 2; kk++) {
            h8 kf[4];
#pragma unroll
            for (int in = 0; in < 4; in++) {
                int row = in * 16 + (lane & 15);
                int pc = (kk * 4 + (lane >> 4)) ^ (row & 7);
                kf[in] = *(const h8*)(&lK[cur][0] + row * 64 + pc * 8);
            }
#pragma unroll
            for (int im = 0; im < 2; im++)
#pragma unroll
                for (int in = 0; in < 4; in++)
                    sacc[im][in] = MFMA(qf[im][kk], kf[in], sacc[im][in]);
        }
        __builtin_amdgcn_s_setprio(0);

        const bool msk = (k0 + 63 > qw);
#pragma unroll
        for (int im = 0; im < 2; im++) {
#pragma unroll
            for (int r = 0; r < 4; r++) {
                float vmax = -3e38f;
#pragma unroll
                for (int in = 0; in < 4; in++) {
                    float s = sacc[im][in][r] * 0.125f;
                    if (msk) {
                        int q = qw + im * 16 + (lane >> 4) * 4 + r;
                        int k = k0 + in * 16 + (lane & 15);
                        if (k > q) s = -3e38f;
                    }
                    sacc[im][in][r] = s;
                    vmax = fmaxf(vmax, s);
                }
                vmax = rmax16(vmax);
                float mnew = fmaxf(mrun[im][r], vmax);
                float scal = __expf(mrun[im][r] - mnew);
                float ls = 0.f;
#pragma unroll
                for (int in = 0; in < 4; in++) {
                    float p = __expf(sacc[im][in][r] - mnew);
                    sacc[im][in][r] = p;
                    ls += p;
                }
                lpart[im][r] = lpart[im][r] * scal + ls;  // per-lane partial; reduce after loop
                mrun[im][r] = mnew;
#pragma unroll
                for (int dn = 0; dn < 4; dn++) yacc[im][dn][r] *= scal;
            }
        }

        // write P (f16) to per-wave swizzled LDS
#pragma unroll
        for (int im = 0; im < 2; im++)
#pragma unroll
            for (int in = 0; in < 4; in++)
#pragma unroll
                for (int r = 0; r < 4; r++) {
                    int row = im * 16 + (lane >> 4) * 4 + r;
                    int col = in * 16 + (lane & 15);
                    lPw[row * 64 + (((col >> 3) ^ (row & 7)) * 8) + (col & 7)] =
                        (f16)sacc[im][in][r];
                }

        // Y += P V
        __builtin_amdgcn_s_setprio(1);
#pragma unroll
        for (int kk = 0; kk < 2; kk++) {
            h8 pf[2], vf[4];
#pragma unroll
            for (int im = 0; im < 2; im++) {
                int row = im * 16 + (lane & 15);
                int pc = (kk * 4 + (lane >> 4)) ^ (row & 7);
                pf[im] = *(const h8*)(lPw + row * 64 + pc * 8);
            }
#pragma unroll
            for (int dn = 0; dn < 4; dn++) {
                int row = dn * 16 + (lane & 15);
                int pc = (kk * 4 + (lane >> 4)) ^ (row & 7);
                vf[dn] = *(const h8*)(&lV[cur][0] + row * 64 + pc * 8);
            }
#pragma unroll
            for (int im = 0; im < 2; im++)
#pragma unroll
                for (int dn = 0; dn < 4; dn++)
                    yacc[im][dn] = MFMA(pf[im], vf[dn], yacc[im][dn]);
        }
        __builtin_amdgcn_s_setprio(0);

        // drain LDS reads before other waves may overwrite lK/lV[cur] next iteration
        asm volatile("s_waitcnt lgkmcnt(0)" ::: "memory");
        __builtin_amdgcn_sched_barrier(0);
        __builtin_amdgcn_s_barrier();
        __builtin_amdgcn_sched_barrier(0);
    }

    const int b = bh >> 4, hh = bh & 15;
#pragma unroll
    for (int im = 0; im < 2; im++) {
#pragma unroll
        for (int r = 0; r < 4; r++) {
            float inv = 1.0f / rsum16(lpart[im][r]);
#pragma unroll
            for (int dn = 0; dn < 4; dn++) {
                int q = qw + im * 16 + (lane >> 4) * 4 + r;
                int d = dn * 16 + (lane & 15);
                O[((size_t)(b * 2048 + q)) * 1024 + hh * 64 + d] =
                    (f16)(yacc[im][dn][r] * inv);
            }
        }
    }
}

// ---------------- launch ----------------

extern "C" void kernel_launch(void* const* d_in, const int* in_sizes, int n_in,
                              void* d_out, int out_size, void* d_ws, size_t ws_size,
                              hipStream_t stream) {
    const float* x      = (const float*)d_in[0];
    const float* W_attn = (const float*)d_in[1];
    const float* b_attn = (const float*)d_in[2];
    const float* W_proj = (const float*)d_in[3];
    const float* b_proj = (const float*)d_in[4];
    float* out = (float*)d_out;

    char* ws = (char*)d_ws;
    f16* xb  = (f16*)ws;                                   // 16 MB (reused as attn out)
    f16* Wat = (f16*)(ws + 16777216);                      // 6 MB
    f16* Wpt = (f16*)(ws + 16777216 + 6291456);            // 2 MB
    f16* Vt  = (f16*)(ws + 16777216 + 6291456 + 2097152);  // 16 MB
    f16* Qs  = (f16*)d_out;                                // scratch: first 16 MB of out
    f16* Ks  = (f16*)((char*)d_out + 16777216);            // scratch: second 16 MB of out

    cvt_f16_kernel<<<4096, 256, 0, stream>>>(x, xb, 1048576);
    transpose_cvt<<<dim3(96, 32), dim3(32, 8), 0, stream>>>(W_attn, Wat, 1024, 3072);
    transpose_cvt<<<dim3(32, 32), dim3(32, 8), 0, stream>>>(W_proj, Wpt, 1024, 1024);
    qkv_gemm<<<1536, 256, 0, stream>>>(xb, Wat, b_attn, Qs, Ks, Vt);
    attn_kernel<<<1024, 256, 0, stream>>>(Qs, Ks, Vt, xb);
    proj_gemm<<<512, 256, 0, stream>>>(xb, Wpt, b_proj, out);
}

// Round 4
// 248.274 us; speedup vs baseline: 2.0875x; 1.0121x over previous
//
#include <hip/hip_runtime.h>

typedef _Float16 f16;
typedef __attribute__((ext_vector_type(8))) _Float16 h8;
typedef __attribute__((ext_vector_type(4))) _Float16 h4;
typedef __attribute__((ext_vector_type(4))) float f4;

#define MFMA(a, b, c) __builtin_amdgcn_mfma_f32_16x16x32_f16(a, b, c, 0, 0, 0)

// Q prescale: 1/sqrt(64) * log2(e), folded into qkv epilogue -> softmax in base-2
#define QSCALE 0.18033688011112042f

__device__ __forceinline__ void gload16(const void* g, void* l) {
    __builtin_amdgcn_global_load_lds((const __attribute__((address_space(1))) void*)g,
                                     (__attribute__((address_space(3))) void*)l, 16, 0, 0);
}

__device__ __forceinline__ float fexp2(float x) {
    float r;
    asm("v_exp_f32 %0, %1" : "=v"(r) : "v"(x));
    return r;
}

__device__ __forceinline__ float rmax16(float v) {
#pragma unroll
    for (int m = 1; m < 16; m <<= 1) v = fmaxf(v, __shfl_xor(v, m));
    return v;
}
__device__ __forceinline__ float rsum16(float v) {
#pragma unroll
    for (int m = 1; m < 16; m <<= 1) v += __shfl_xor(v, m);
    return v;
}

// ---------------- conversion kernels ----------------

__global__ __launch_bounds__(256) void cvt_f16_kernel(const float* __restrict__ in,
                                                      f16* __restrict__ out, int n8) {
    int i = blockIdx.x * blockDim.x + threadIdx.x;
    if (i >= n8) return;
    const float4* p = (const float4*)in + (size_t)i * 2;
    float4 a = p[0], b = p[1];
    h8 o;
    o[0] = (f16)a.x; o[1] = (f16)a.y; o[2] = (f16)a.z; o[3] = (f16)a.w;
    o[4] = (f16)b.x; o[5] = (f16)b.y; o[6] = (f16)b.z; o[7] = (f16)b.w;
    *((h8*)out + i) = o;
}

// in: [R][Cc] f32 row-major -> out: [Cc][R] f16 row-major
__global__ __launch_bounds__(256) void transpose_cvt(const float* __restrict__ in,
                                                     f16* __restrict__ out, int R, int Cc) {
    __shared__ float tile[32][33];
    int tx = threadIdx.x, ty = threadIdx.y;
    int c0 = blockIdx.x * 32, r0 = blockIdx.y * 32;
#pragma unroll
    for (int k = 0; k < 32; k += 8)
        tile[ty + k][tx] = in[(size_t)(r0 + ty + k) * Cc + c0 + tx];
    __syncthreads();
#pragma unroll
    for (int k = 0; k < 32; k += 8)
        out[(size_t)(c0 + ty + k) * R + r0 + tx] = (f16)tile[tx][ty + k];
}

// ---------------- GEMM core (128x128 tile, BK=64, 4 waves, swizzled LDS) ----------------

__device__ __forceinline__ void gemm_core(const f16* __restrict__ A, const f16* __restrict__ Bt,
                                          int K, int m0, int n0,
                                          f16* lA, f16* lB, f4 acc[4][4]) {
    const int tid = threadIdx.x, lane = tid & 63, wave = tid >> 6;
    const int wm = (wave >> 1) * 64, wn = (wave & 1) * 64;
    for (int k0 = 0; k0 < K; k0 += 64) {
        __syncthreads();
#pragma unroll
        for (int i = 0; i < 4; i++) {
            int s = i * 256 + wave * 64 + lane;
            int row = s >> 3;
            int gc = ((s & 7) ^ (row & 7)) * 8;
            gload16(A + (size_t)(m0 + row) * K + k0 + gc, lA + (i * 256 + wave * 64) * 8);
        }
#pragma unroll
        for (int i = 0; i < 4; i++) {
            int s = i * 256 + wave * 64 + lane;
            int row = s >> 3;
            int gc = ((s & 7) ^ (row & 7)) * 8;
            gload16(Bt + (size_t)(n0 + row) * K + k0 + gc, lB + (i * 256 + wave * 64) * 8);
        }
        __syncthreads();
#pragma unroll
        for (int kk = 0; kk < 2; kk++) {
            h8 af[4], bg[4];
#pragma unroll
            for (int im = 0; im < 4; im++) {
                int row = wm + im * 16 + (lane & 15);
                int pc = (kk * 4 + (lane >> 4)) ^ (row & 7);
                af[im] = *(const h8*)(lA + row * 64 + pc * 8);
            }
#pragma unroll
            for (int in = 0; in < 4; in++) {
                int row = wn + in * 16 + (lane & 15);
                int pc = (kk * 4 + (lane >> 4)) ^ (row & 7);
                bg[in] = *(const h8*)(lB + row * 64 + pc * 8);
            }
#pragma unroll
            for (int im = 0; im < 4; im++)
#pragma unroll
                for (int in = 0; in < 4; in++)
                    acc[im][in] = MFMA(af[im], bg[in], acc[im][in]);
        }
    }
}

// ---------------- QKV GEMM: writes Q (prescaled), K [BH][T][64], V^T [BH][64][T] ----------------

__global__ __launch_bounds__(256) void qkv_gemm(const f16* __restrict__ A, const f16* __restrict__ Bt,
                                                const float* __restrict__ bias,
                                                f16* __restrict__ Qo, f16* __restrict__ Ko,
                                                f16* __restrict__ Vo) {
    __shared__ f16 lA[128 * 64], lB[128 * 64];
    f4 acc[4][4];
    const f4 zz = {0.f, 0.f, 0.f, 0.f};
#pragma unroll
    for (int i = 0; i < 4; i++)
#pragma unroll
        for (int j = 0; j < 4; j++) acc[i][j] = zz;

    const int swz = (blockIdx.x & 7) * 192 + (blockIdx.x >> 3);  // XCD-chunked (1536 = 8*192)
    const int nb = swz % 24, mb = swz / 24;
    gemm_core(A, Bt, 1024, mb * 128, nb * 128, lA, lB, acc);

    const int lane = threadIdx.x & 63, wave = threadIdx.x >> 6;
    const int wm = (wave >> 1) * 64, wn = (wave & 1) * 64;
#pragma unroll
    for (int im = 0; im < 4; im++) {
        int m4 = mb * 128 + wm + im * 16 + (lane >> 4) * 4;
        int b = m4 >> 11, t0 = m4 & 2047;
#pragma unroll
        for (int in = 0; in < 4; in++) {
            int n = nb * 128 + wn + in * 16 + (lane & 15);
            float bb = bias[n];
            int sec = n >> 10, cc = n & 1023, hh = cc >> 6, d = cc & 63;
            if (sec == 2) {
                h4 pv;
#pragma unroll
                for (int r = 0; r < 4; r++) pv[r] = (f16)(acc[im][in][r] + bb);
                *(h4*)(Vo + ((size_t)(b * 16 + hh) * 64 + d) * 2048 + t0) = pv;
            } else {
                f16* dst = sec ? Ko : Qo;
                float sc = sec ? 1.0f : QSCALE;  // Q prescaled for base-2 softmax
                size_t base = ((size_t)(b * 16 + hh) * 2048 + t0) * 64 + d;
#pragma unroll
                for (int r = 0; r < 4; r++)
                    dst[base + (size_t)r * 64] = (f16)((acc[im][in][r] + bb) * sc);
            }
        }
    }
}

// ---------------- Proj GEMM: f32 output + bias ----------------

__global__ __launch_bounds__(256) void proj_gemm(const f16* __restrict__ A, const f16* __restrict__ Bt,
                                                 const float* __restrict__ bias,
                                                 float* __restrict__ out) {
    __shared__ f16 lA[128 * 64], lB[128 * 64];
    f4 acc[4][4];
    const f4 zz = {0.f, 0.f, 0.f, 0.f};
#pragma unroll
    for (int i = 0; i < 4; i++)
#pragma unroll
        for (int j = 0; j < 4; j++) acc[i][j] = zz;

    const int swz = (blockIdx.x & 7) * 64 + (blockIdx.x >> 3);  // XCD-chunked (512 = 8*64)
    const int nb = swz & 7, mb = swz >> 3;
    gemm_core(A, Bt, 1024, mb * 128, nb * 128, lA, lB, acc);

    const int lane = threadIdx.x & 63, wave = threadIdx.x >> 6;
    const int wm = (wave >> 1) * 64, wn = (wave & 1) * 64;
#pragma unroll
    for (int im = 0; im < 4; im++) {
        int m4 = mb * 128 + wm + im * 16 + (lane >> 4) * 4;
#pragma unroll
        for (int in = 0; in < 4; in++) {
            int n = nb * 128 + wn + in * 16 + (lane & 15);
            float bb = bias[n];
#pragma unroll
            for (int r = 0; r < 4; r++)
                out[(size_t)(m4 + r) * 1024 + n] = acc[im][in][r] + bb;
        }
    }
}

// ---------------- Flash attention (causal, base-2 softmax, defer-max) ----------------
// Q(prescaled),K: [BH][2048][64] f16; Vg: [BH][64][2048] f16 (transposed); O: [B][2048][1024] f16
// 1 block = 128 q-rows; 4 waves x 32 rows; KV tiles of 64.
// K double-buffered LDS via global_load_lds + counted vmcnt(2); V direct from global (L2).
// Defer-max (THR=8 in log2 units): skip 16-lane max reduce + rescale when safe.

#define ASM_VMCNT(N) asm volatile("s_waitcnt vmcnt(" #N ")" ::: "memory")

__global__ __launch_bounds__(256) void attn_kernel(const f16* __restrict__ Q, const f16* __restrict__ K,
                                                   const f16* __restrict__ Vg, f16* __restrict__ O) {
    __shared__ f16 lK[2][64 * 64];
    __shared__ f16 lP[4 * 32 * 64];
    const int tid = threadIdx.x, lane = tid & 63, wave = tid >> 6;
    const int bh = blockIdx.x & 63;
    const int g = blockIdx.x >> 6;
    const int qb = (int)((0x75318ACE64209BDFull >> (g * 4)) & 15);
    const int q0 = qb * 128;
    const int qw = q0 + wave * 32;
    const f16* Qb = Q + (size_t)bh * 2048 * 64;
    const f16* Kb = K + (size_t)bh * 2048 * 64;
    const f16* Vb = Vg + (size_t)bh * 64 * 2048;
    f16* lPw = lP + wave * 32 * 64;

    // hoist Q fragments (A-operand layout)
    h8 qf[2][2];
#pragma unroll
    for (int im = 0; im < 2; im++)
#pragma unroll
        for (int kk = 0; kk < 2; kk++) {
            int t = qw + im * 16 + (lane & 15);
            qf[im][kk] = *(const h8*)(Qb + (size_t)t * 64 + kk * 32 + (lane >> 4) * 8);
        }

    float mrun[2][4], lpart[2][4];
    f4 yacc[2][4];
    const f4 zz = {0.f, 0.f, 0.f, 0.f};
#pragma unroll
    for (int im = 0; im < 2; im++) {
#pragma unroll
        for (int r = 0; r < 4; r++) { mrun[im][r] = -3e38f; lpart[im][r] = 0.f; }
#pragma unroll
        for (int dn = 0; dn < 4; dn++) yacc[im][dn] = zz;
    }

    const int nt = q0 / 64 + 2;

    // prologue: stage K tile 0 into buffer 0
#pragma unroll
    for (int i = 0; i < 2; i++) {
        int s = i * 256 + wave * 64 + lane;
        int row = s >> 3;
        int gc = ((s & 7) ^ (row & 7)) * 8;
        gload16(Kb + (size_t)row * 64 + gc, &lK[0][(i * 256 + wave * 64) * 8]);
    }

    for (int it = 0; it < nt; it++) {
        const int cur = it & 1;
        const int k0 = it * 64;

        if (it + 1 < nt) {
#pragma unroll
            for (int i = 0; i < 2; i++) {
                int s = i * 256 + wave * 64 + lane;
                int row = s >> 3;
                int gc = ((s & 7) ^ (row & 7)) * 8;
                gload16(Kb + (size_t)(k0 + 64 + row) * 64 + gc, &lK[cur ^ 1][(i * 256 + wave * 64) * 8]);
            }
            ASM_VMCNT(2);  // wait only for current tile's 2 loads
        } else {
            ASM_VMCNT(0);
        }
        __builtin_amdgcn_sched_barrier(0);
        __builtin_amdgcn_s_barrier();
        __builtin_amdgcn_sched_barrier(0);

        const bool active = (k0 <= qw + 31);  // skip fully-masked tiles (barriers still hit)
        if (active) {
            // S = Q K^T  (pre-scaled: S is already in log2 units)
            f4 sacc[2][4];
#pragma unroll
            for (int im = 0; im < 2; im++)
#pragma unroll
                for (int in = 0; in < 4; in++) sacc[im][in] = zz;
            __builtin_amdgcn_s_setprio(1);
#pragma unroll
            for (int kk = 0; kk < 2; kk++) {
                h8 kf[4];
#pragma unroll
                for (int in = 0; in < 4; in++) {
                    int row = in * 16 + (lane & 15);
                    int pc = (kk * 4 + (lane >> 4)) ^ (row & 7);
                    kf[in] = *(const h8*)(&lK[cur][0] + row * 64 + pc * 8);
                }
#pragma unroll
                for (int im = 0; im < 2; im++)
#pragma unroll
                    for (int in = 0; in < 4; in++)
                        sacc[im][in] = MFMA(qf[im][kk], kf[in], sacc[im][in]);
            }
            __builtin_amdgcn_s_setprio(0);

            const bool msk = (k0 + 63 > qw);
            if (msk) {
#pragma unroll
                for (int im = 0; im < 2; im++)
#pragma unroll
                    for (int in = 0; in < 4; in++)
#pragma unroll
                        for (int r = 0; r < 4; r++) {
                            int q = qw + im * 16 + (lane >> 4) * 4 + r;
                            int k = k0 + in * 16 + (lane & 15);
                            if (k > q) sacc[im][in][r] = -3e38f;
                        }
            }

#pragma unroll
            for (int im = 0; im < 2; im++) {
#pragma unroll
                for (int r = 0; r < 4; r++) {
                    float a0 = fmaxf(sacc[im][0][r], sacc[im][1][r]);
                    float a1 = fmaxf(sacc[im][2][r], sacc[im][3][r]);
                    float vmax4 = fmaxf(a0, a1);
                    if (!__all(vmax4 <= mrun[im][r] + 8.0f)) {
                        float vmax = rmax16(vmax4);
                        float mnew = fmaxf(mrun[im][r], vmax);
                        float sc = fexp2(mrun[im][r] - mnew);
                        lpart[im][r] *= sc;
#pragma unroll
                        for (int dn = 0; dn < 4; dn++) yacc[im][dn][r] *= sc;
                        mrun[im][r] = mnew;
                    }
                    float m = mrun[im][r];
                    float ls = 0.f;
#pragma unroll
                    for (int in = 0; in < 4; in++) {
                        float p = fexp2(sacc[im][in][r] - m);
                        sacc[im][in][r] = p;
                        ls += p;
                    }
                    lpart[im][r] += ls;
                }
            }

            // write P (f16) to per-wave swizzled LDS
#pragma unroll
            for (int im = 0; im < 2; im++)
#pragma unroll
                for (int in = 0; in < 4; in++)
#pragma unroll
                    for (int r = 0; r < 4; r++) {
                        int row = im * 16 + (lane >> 4) * 4 + r;
                        int col = in * 16 + (lane & 15);
                        lPw[row * 64 + (((col >> 3) ^ (row & 7)) * 8) + (col & 7)] =
                            (f16)sacc[im][in][r];
                    }

            // Y += P V   (V fragments direct from global; per-bh V panel is L2-resident)
            __builtin_amdgcn_s_setprio(1);
#pragma unroll
            for (int kk = 0; kk < 2; kk++) {
                h8 pf[2], vf[4];
#pragma unroll
                for (int dn = 0; dn < 4; dn++)
                    vf[dn] = *(const h8*)(Vb + (size_t)(dn * 16 + (lane & 15)) * 2048 + k0 +
                                          kk * 32 + (lane >> 4) * 8);
#pragma unroll
                for (int im = 0; im < 2; im++) {
                    int row = im * 16 + (lane & 15);
                    int pc = (kk * 4 + (lane >> 4)) ^ (row & 7);
                    pf[im] = *(const h8*)(lPw + row * 64 + pc * 8);
                }
#pragma unroll
                for (int im = 0; im < 2; im++)
#pragma unroll
                    for (int dn = 0; dn < 4; dn++)
                        yacc[im][dn] = MFMA(pf[im], vf[dn], yacc[im][dn]);
            }
            __builtin_amdgcn_s_setprio(0);
        }

        // drain LDS reads before other waves may overwrite lK[cur] next iteration
        asm volatile("s_waitcnt lgkmcnt(0)" ::: "memory");
        __builtin_amdgcn_sched_barrier(0);
        __builtin_amdgcn_s_barrier();
        __builtin_amdgcn_sched_barrier(0);
    }

    const int b = bh >> 4, hh = bh & 15;
#pragma unroll
    for (int im = 0; im < 2; im++) {
#pragma unroll
        for (int r = 0; r < 4; r++) {
            float inv = 1.0f / rsum16(lpart[im][r]);
#pragma unroll
            for (int dn = 0; dn < 4; dn++) {
                int q = qw + im * 16 + (lane >> 4) * 4 + r;
                int d = dn * 16 + (lane & 15);
                O[((size_t)(b * 2048 + q)) * 1024 + hh * 64 + d] =
                    (f16)(yacc[im][dn][r] * inv);
            }
        }
    }
}

// ---------------- launch ----------------

extern "C" void kernel_launch(void* const* d_in, const int* in_sizes, int n_in,
                              void* d_out, int out_size, void* d_ws, size_t ws_size,
                              hipStream_t stream) {
    const float* x      = (const float*)d_in[0];
    const float* W_attn = (const float*)d_in[1];
    const float* b_attn = (const float*)d_in[2];
    const float* W_proj = (const float*)d_in[3];
    const float* b_proj = (const float*)d_in[4];
    float* out = (float*)d_out;

    char* ws = (char*)d_ws;
    f16* xb  = (f16*)ws;                                   // 16 MB (reused as attn out)
    f16* Wat = (f16*)(ws + 16777216);                      // 6 MB
    f16* Wpt = (f16*)(ws + 16777216 + 6291456);            // 2 MB
    f16* Vt  = (f16*)(ws + 16777216 + 6291456 + 2097152);  // 16 MB
    f16* Qs  = (f16*)d_out;                                // scratch: first 16 MB of out
    f16* Ks  = (f16*)((char*)d_out + 16777216);            // scratch: second 16 MB of out

    cvt_f16_kernel<<<4096, 256, 0, stream>>>(x, xb, 1048576);
    transpose_cvt<<<dim3(96, 32), dim3(32, 8), 0, stream>>>(W_attn, Wat, 1024, 3072);
    transpose_cvt<<<dim3(32, 32), dim3(32, 8), 0, stream>>>(W_proj, Wpt, 1024, 1024);
    qkv_gemm<<<1536, 256, 0, stream>>>(xb, Wat, b_attn, Qs, Ks, Vt);
    attn_kernel<<<1024, 256, 0, stream>>>(Qs, Ks, Vt, xb);
    proj_gemm<<<512, 256, 0, stream>>>(xb, Wpt, b_proj, out);
}